// Round 5
// baseline (280.237 us; speedup 1.0000x reference)
//
#include <hip/hip_runtime.h>
#include <hip/hip_bf16.h>
#include <math.h>

#define N_NODES 100000
#define E_EDGES 1600000
#define IN_F 256
#define OUT_F 128
#define LRELU_ALPHA 0.2f

typedef __attribute__((ext_vector_type(8))) short bf16x8;
typedef __attribute__((ext_vector_type(4))) float f32x4;

__device__ __forceinline__ unsigned short f32_to_bf16(float f) {
  unsigned int u = __float_as_uint(f);
  u = (u + 0x7fffu + ((u >> 16) & 1u)) >> 16;  // round-to-nearest-even
  return (unsigned short)u;
}
// packed fp32x2 -> bf16x2 (low = a, high = b); uses v_cvt_pk_bf16_f32 on gfx950
__device__ __forceinline__ unsigned cvt2(float a, float b) {
  __hip_bfloat162 v = __float22bfloat162_rn(make_float2(a, b));
  unsigned u;
  __builtin_memcpy(&u, &v, 4);
  return u;
}

// ---------------------------------------------------------------------------
// Prep (merged): blocks [0,390]: row_ptr binary search + zero f1/f2;
//                blocks [391,518]: Wt16[n][k] = bf16(W[k][n]).
// ---------------------------------------------------------------------------
#define ROWPTR_BLOCKS 391
__global__ void prep_kernel(const int* __restrict__ row,
                            int* __restrict__ row_ptr, float* __restrict__ f1,
                            float* __restrict__ f2, const float* __restrict__ W,
                            unsigned short* __restrict__ Wt16) {
  const int b = blockIdx.x;
  if (b < ROWPTR_BLOCKS) {
    const int i = b * 256 + threadIdx.x;
    if (i > N_NODES) return;
    int lo = 0, hi = E_EDGES;
    while (lo < hi) {
      const int mid = (lo + hi) >> 1;
      if (row[mid] < i) lo = mid + 1; else hi = mid;
    }
    row_ptr[i] = lo;
    if (i < N_NODES) { f1[i] = 0.f; f2[i] = 0.f; }
  } else {
    const int idx = (b - ROWPTR_BLOCKS) * 256 + threadIdx.x;  // 0..32767
    const int n = idx >> 8;
    const int k = idx & 255;
    Wt16[n * IN_F + k] = f32_to_bf16(W[k * OUT_F + n]);
  }
}

// ---------------------------------------------------------------------------
// Kernel 1: Wh16 = bf16(h @ W) via MFMA 16x16x32_bf16.
// Block 128x128, BK=32, 256 threads = 4 waves (2x2), each wave 64x64 = 4x4
// tiles. h converted fp32->bf16 during staging via packed HW cvt. Fused
// epilogue: f1/f2 dots + shuffle reduce + atomicAdd; C staged via LDS.
// ---------------------------------------------------------------------------
#define AS_STRIDE 40
#define OS_STRIDE 136
__global__ __launch_bounds__(256) void gemm_mfma(
    const float* __restrict__ h, const unsigned short* __restrict__ Wt16,
    const float* __restrict__ a_src, const float* __restrict__ a_dst,
    unsigned short* __restrict__ Wh16, float* __restrict__ f1,
    float* __restrict__ f2) {
  __shared__ unsigned short lds[128 * OS_STRIDE];  // 34816 B
  unsigned short* As = lds;                        // [128][40]
  unsigned short* Bs = lds + 128 * AS_STRIDE;      // [128][40]

  const int tid = threadIdx.x;
  const int lane = tid & 63;
  const int w = tid >> 6;        // wave 0..3
  const int wr = w >> 1;         // wave row 0..1 (x64 rows)
  const int wc = w & 1;          // wave col 0..1 (x64 cols)
  const int quad = lane >> 4;    // 0..3
  const int lm = lane & 15;      // m/n within tile
  const int m0 = blockIdx.x * 128;

  const int srow = tid >> 1;     // staging row 0..127
  const int shalf = tid & 1;     // staging k-half (16 elements)

  f32x4 acc[4][4];
#pragma unroll
  for (int a = 0; a < 4; ++a)
#pragma unroll
    for (int b = 0; b < 4; ++b) acc[a][b] = (f32x4){0.f, 0.f, 0.f, 0.f};

  const int gr = min(m0 + srow, N_NODES - 1);  // clamp tail-block loads

  for (int k0 = 0; k0 < IN_F; k0 += 32) {
    // global loads for this tile
    const float4* hp =
        reinterpret_cast<const float4*>(&h[gr * IN_F + k0 + shalf * 16]);
    const float4 h0 = hp[0], h1 = hp[1], h2 = hp[2], h3 = hp[3];
    const uint4* wp = reinterpret_cast<const uint4*>(
        &Wt16[srow * IN_F + k0 + shalf * 16]);
    const uint4 wv0 = wp[0], wv1 = wp[1];

    __syncthreads();  // previous tile's LDS reads complete
    {
      uint4 p0, p1;
      p0.x = cvt2(h0.x, h0.y); p0.y = cvt2(h0.z, h0.w);
      p0.z = cvt2(h1.x, h1.y); p0.w = cvt2(h1.z, h1.w);
      p1.x = cvt2(h2.x, h2.y); p1.y = cvt2(h2.z, h2.w);
      p1.z = cvt2(h3.x, h3.y); p1.w = cvt2(h3.z, h3.w);
      uint4* as = reinterpret_cast<uint4*>(&As[srow * AS_STRIDE + shalf * 16]);
      as[0] = p0; as[1] = p1;
      uint4* bs = reinterpret_cast<uint4*>(&Bs[srow * AS_STRIDE + shalf * 16]);
      bs[0] = wv0; bs[1] = wv1;
    }
    __syncthreads();

    bf16x8 af[4], bf[4];
#pragma unroll
    for (int t = 0; t < 4; ++t) {
      af[t] = *reinterpret_cast<const bf16x8*>(
          &As[(wr * 64 + t * 16 + lm) * AS_STRIDE + quad * 8]);
      bf[t] = *reinterpret_cast<const bf16x8*>(
          &Bs[(wc * 64 + t * 16 + lm) * AS_STRIDE + quad * 8]);
    }
#pragma unroll
    for (int tr = 0; tr < 4; ++tr)
#pragma unroll
      for (int tc = 0; tc < 4; ++tc)
        acc[tr][tc] = __builtin_amdgcn_mfma_f32_16x16x32_bf16(
            af[tr], bf[tc], acc[tr][tc], 0, 0, 0);
  }

  // ---- epilogue 1: fused f1/f2 (lane holds rows quad*4+reg per tile)
  float asv[4], adv[4];
#pragma unroll
  for (int tc = 0; tc < 4; ++tc) {
    asv[tc] = a_src[wc * 64 + tc * 16 + lm];
    adv[tc] = a_dst[wc * 64 + tc * 16 + lm];
  }
#pragma unroll
  for (int tr = 0; tr < 4; ++tr) {
#pragma unroll
    for (int reg = 0; reg < 4; ++reg) {
      float p1 = 0.f, p2 = 0.f;
#pragma unroll
      for (int tc = 0; tc < 4; ++tc) {
        p1 = fmaf(acc[tr][tc][reg], asv[tc], p1);
        p2 = fmaf(acc[tr][tc][reg], adv[tc], p2);
      }
#pragma unroll
      for (int o = 1; o < 16; o <<= 1) {  // reduce the 16 lm lanes
        p1 += __shfl_xor(p1, o);
        p2 += __shfl_xor(p2, o);
      }
      const int grow = m0 + wr * 64 + tr * 16 + quad * 4 + reg;
      if (lm == 0 && grow < N_NODES) {
        atomicAdd(&f1[grow], p1);
        atomicAdd(&f2[grow], p2);
      }
    }
  }

  // ---- epilogue 2: stage C tile to LDS (bf16), then coalesced global copy
  __syncthreads();  // done with As/Bs
#pragma unroll
  for (int tr = 0; tr < 4; ++tr)
#pragma unroll
    for (int tc = 0; tc < 4; ++tc)
#pragma unroll
      for (int reg = 0; reg < 4; ++reg)
        lds[(wr * 64 + tr * 16 + quad * 4 + reg) * OS_STRIDE + wc * 64 +
            tc * 16 + lm] = f32_to_bf16(acc[tr][tc][reg]);
  __syncthreads();
  // each (srow, shalf) thread copies 64 contiguous ushorts = 8 uint4
  if (m0 + srow < N_NODES) {
    uint4* dst =
        reinterpret_cast<uint4*>(&Wh16[(m0 + srow) * OUT_F + shalf * 64]);
    const uint4* src =
        reinterpret_cast<const uint4*>(&lds[srow * OS_STRIDE + shalf * 64]);
#pragma unroll
    for (int i = 0; i < 8; ++i) dst[i] = src[i];
  }
}

// ---------------------------------------------------------------------------
// Kernel 2: segment softmax + SpMM + ELU. One wave per node, 4 nodes/block.
// Pass C processes 4 EDGES PER ITERATION: lane = (g,j), g=lane>>4 owns edge
// e0+g, lane j gathers uint4 (8 features, 16B) -> one wave-instr gathers 4
// full 256B rows. Cross-group shfl_xor(16/32) reduce; g==0 lanes write out.
// ---------------------------------------------------------------------------
__global__ __launch_bounds__(256) void gat_v3(
    const uint4* __restrict__ Whv,  // Wh16 viewed as [N][16] uint4 rows
    const float* __restrict__ f1, const float* __restrict__ f2,
    const int* __restrict__ row_ptr, const int* __restrict__ col,
    float* __restrict__ out) {
  __shared__ int2 edge_s[4][128];

  const int w = threadIdx.x >> 6;
  const int lane = threadIdx.x & 63;
  const int g = lane >> 4;   // edge group 0..3
  const int j = lane & 15;   // feature chunk 0..15 (8 features each)
  const int node = blockIdx.x * 4 + w;

  const int start = row_ptr[node];
  const int deg = row_ptr[node + 1] - start;

  if (deg == 0) {
    if (g == 0) {
      const float4 z = {0.f, 0.f, 0.f, 0.f};
      float4* op = reinterpret_cast<float4*>(&out[node * OUT_F + j * 8]);
      op[0] = z; op[1] = z;
    }
    return;
  }
  const float f1i = f1[node];
  float acc[8] = {0.f, 0.f, 0.f, 0.f, 0.f, 0.f, 0.f, 0.f};
  float m = -INFINITY, s = 0.f, inv;

  if (deg <= 128) {
    // pass A: logits -> LDS, running max
    for (int idx = lane; idx < deg; idx += 64) {
      const int c = col[start + idx];
      float v = f1i + f2[c];
      v = v > 0.f ? v : LRELU_ALPHA * v;
      edge_s[w][idx] = make_int2(__float_as_int(v), c);
      m = fmaxf(m, v);
    }
#pragma unroll
    for (int o = 32; o > 0; o >>= 1) m = fmaxf(m, __shfl_xor(m, o));
    __builtin_amdgcn_wave_barrier();
    // pass B: exp + sum (store numerator back)
    for (int idx = lane; idx < deg; idx += 64) {
      const float x = __expf(__int_as_float(edge_s[w][idx].x) - m);
      edge_s[w][idx].x = __float_as_int(x);
      s += x;
    }
#pragma unroll
    for (int o = 32; o > 0; o >>= 1) s += __shfl_xor(s, o);
    inv = 1.f / s;
    __builtin_amdgcn_wave_barrier();
    // pass C: 4 edges per iteration
    for (int e0 = 0; e0 < deg; e0 += 4) {
      const int e = e0 + g;
      if (e < deg) {
        const int2 ec = edge_s[w][e];  // b64 broadcast within group
        const float a = __int_as_float(ec.x);
        const uint4 gv = Whv[ec.y * 16 + j];
        acc[0] = fmaf(a, __uint_as_float(gv.x << 16), acc[0]);
        acc[1] = fmaf(a, __uint_as_float(gv.x & 0xffff0000u), acc[1]);
        acc[2] = fmaf(a, __uint_as_float(gv.y << 16), acc[2]);
        acc[3] = fmaf(a, __uint_as_float(gv.y & 0xffff0000u), acc[3]);
        acc[4] = fmaf(a, __uint_as_float(gv.z << 16), acc[4]);
        acc[5] = fmaf(a, __uint_as_float(gv.z & 0xffff0000u), acc[5]);
        acc[6] = fmaf(a, __uint_as_float(gv.w << 16), acc[6]);
        acc[7] = fmaf(a, __uint_as_float(gv.w & 0xffff0000u), acc[7]);
      }
    }
  } else {
    // slow path (deg > 128, ~never with Poisson(16) degrees): recompute
    for (int idx = lane; idx < deg; idx += 64) {
      float v = f1i + f2[col[start + idx]];
      v = v > 0.f ? v : LRELU_ALPHA * v;
      m = fmaxf(m, v);
    }
#pragma unroll
    for (int o = 32; o > 0; o >>= 1) m = fmaxf(m, __shfl_xor(m, o));
    for (int idx = lane; idx < deg; idx += 64) {
      float v = f1i + f2[col[start + idx]];
      v = v > 0.f ? v : LRELU_ALPHA * v;
      s += __expf(v - m);
    }
#pragma unroll
    for (int o = 32; o > 0; o >>= 1) s += __shfl_xor(s, o);
    inv = 1.f / s;
    for (int e0 = 0; e0 < deg; e0 += 4) {
      const int e = e0 + g;
      if (e < deg) {
        const int c = col[start + e];
        float v = f1i + f2[c];
        v = v > 0.f ? v : LRELU_ALPHA * v;
        const float a = __expf(v - m);
        const uint4 gv = Whv[c * 16 + j];
        acc[0] = fmaf(a, __uint_as_float(gv.x << 16), acc[0]);
        acc[1] = fmaf(a, __uint_as_float(gv.x & 0xffff0000u), acc[1]);
        acc[2] = fmaf(a, __uint_as_float(gv.y << 16), acc[2]);
        acc[3] = fmaf(a, __uint_as_float(gv.y & 0xffff0000u), acc[3]);
        acc[4] = fmaf(a, __uint_as_float(gv.z << 16), acc[4]);
        acc[5] = fmaf(a, __uint_as_float(gv.z & 0xffff0000u), acc[5]);
        acc[6] = fmaf(a, __uint_as_float(gv.w << 16), acc[6]);
        acc[7] = fmaf(a, __uint_as_float(gv.w & 0xffff0000u), acc[7]);
      }
    }
  }

  // cross-group reduction: lanes {g*16+j} -> feature j*8+f
#pragma unroll
  for (int f = 0; f < 8; ++f) {
    acc[f] += __shfl_xor(acc[f], 16);
    acc[f] += __shfl_xor(acc[f], 32);
  }
  if (g == 0) {
    float r[8];
#pragma unroll
    for (int f = 0; f < 8; ++f) {
      const float x = acc[f] * inv;
      r[f] = x > 0.f ? x : expm1f(x);  // ELU
    }
    float4* op = reinterpret_cast<float4*>(&out[node * OUT_F + j * 8]);
    op[0] = make_float4(r[0], r[1], r[2], r[3]);
    op[1] = make_float4(r[4], r[5], r[6], r[7]);
  }
}

// ---------------------------------------------------------------------------
extern "C" void kernel_launch(void* const* d_in, const int* in_sizes, int n_in,
                              void* d_out, int out_size, void* d_ws,
                              size_t ws_size, hipStream_t stream) {
  const float* h     = (const float*)d_in[0];
  const float* W     = (const float*)d_in[1];
  const float* a_src = (const float*)d_in[2];
  const float* a_dst = (const float*)d_in[3];
  const int*   row   = (const int*)d_in[4];
  const int*   col   = (const int*)d_in[5];
  float* out = (float*)d_out;

  char* ws = (char*)d_ws;
  unsigned short* Wh16 = (unsigned short*)(ws);        // N*128*2 = 25,600,000 B
  float* f1      = (float*)(ws + 25600000);            //    400,000 B
  float* f2      = (float*)(ws + 26000000);            //    400,000 B
  int*   row_ptr = (int*)  (ws + 26400000);            //    400,004 B
  unsigned short* Wt16 = (unsigned short*)(ws + 26800016);  // 64 KB, align16

  hipLaunchKernelGGL(prep_kernel, dim3(ROWPTR_BLOCKS + 128), dim3(256), 0,
                     stream, row, row_ptr, f1, f2, W, Wt16);
  hipLaunchKernelGGL(gemm_mfma, dim3((N_NODES + 127) / 128), dim3(256), 0,
                     stream, h, Wt16, a_src, a_dst, Wh16, f1, f2);
  hipLaunchKernelGGL(gat_v3, dim3(N_NODES / 4), dim3(256), 0, stream,
                     (const uint4*)Wh16, f1, f2, row_ptr, col, out);
}

// Round 6
// 268.333 us; speedup vs baseline: 1.0444x; 1.0444x over previous
//
#include <hip/hip_runtime.h>
#include <hip/hip_bf16.h>
#include <math.h>

#define N_NODES 100000
#define E_EDGES 1600000
#define IN_F 256
#define OUT_F 128
#define LRELU_ALPHA 0.2f

typedef __attribute__((ext_vector_type(8))) short bf16x8;
typedef __attribute__((ext_vector_type(4))) float f32x4;

__device__ __forceinline__ unsigned short f32_to_bf16(float f) {
  unsigned int u = __float_as_uint(f);
  u = (u + 0x7fffu + ((u >> 16) & 1u)) >> 16;  // round-to-nearest-even
  return (unsigned short)u;
}
// packed fp32x2 -> bf16x2 (low = a, high = b); uses v_cvt_pk_bf16_f32 on gfx950
__device__ __forceinline__ unsigned cvt2(float a, float b) {
  __hip_bfloat162 v = __float22bfloat162_rn(make_float2(a, b));
  unsigned u;
  __builtin_memcpy(&u, &v, 4);
  return u;
}

// ---------------------------------------------------------------------------
// Prep (merged): blocks [0,390]: row_ptr binary search + zero f1/f2;
//                blocks [391,518]: Wt16[n][k] = bf16(W[k][n]).
// ---------------------------------------------------------------------------
#define ROWPTR_BLOCKS 391
__global__ void prep_kernel(const int* __restrict__ row,
                            int* __restrict__ row_ptr, float* __restrict__ f1,
                            float* __restrict__ f2, const float* __restrict__ W,
                            unsigned short* __restrict__ Wt16) {
  const int b = blockIdx.x;
  if (b < ROWPTR_BLOCKS) {
    const int i = b * 256 + threadIdx.x;
    if (i > N_NODES) return;
    int lo = 0, hi = E_EDGES;
    while (lo < hi) {
      const int mid = (lo + hi) >> 1;
      if (row[mid] < i) lo = mid + 1; else hi = mid;
    }
    row_ptr[i] = lo;
    if (i < N_NODES) { f1[i] = 0.f; f2[i] = 0.f; }
  } else {
    const int idx = (b - ROWPTR_BLOCKS) * 256 + threadIdx.x;  // 0..32767
    const int n = idx >> 8;
    const int k = idx & 255;
    Wt16[n * IN_F + k] = f32_to_bf16(W[k * OUT_F + n]);
  }
}

// ---------------------------------------------------------------------------
// Kernel 1: Wh16 = bf16(h @ W) via MFMA 16x16x32_bf16.  (unchanged from R5;
// next round it surfaces in top-5 and gets counter-driven treatment)
// ---------------------------------------------------------------------------
#define AS_STRIDE 40
#define OS_STRIDE 136
__global__ __launch_bounds__(256) void gemm_mfma(
    const float* __restrict__ h, const unsigned short* __restrict__ Wt16,
    const float* __restrict__ a_src, const float* __restrict__ a_dst,
    unsigned short* __restrict__ Wh16, float* __restrict__ f1,
    float* __restrict__ f2) {
  __shared__ unsigned short lds[128 * OS_STRIDE];  // 34816 B
  unsigned short* As = lds;                        // [128][40]
  unsigned short* Bs = lds + 128 * AS_STRIDE;      // [128][40]

  const int tid = threadIdx.x;
  const int lane = tid & 63;
  const int w = tid >> 6;        // wave 0..3
  const int wr = w >> 1;         // wave row 0..1 (x64 rows)
  const int wc = w & 1;          // wave col 0..1 (x64 cols)
  const int quad = lane >> 4;    // 0..3
  const int lm = lane & 15;      // m/n within tile
  const int m0 = blockIdx.x * 128;

  const int srow = tid >> 1;     // staging row 0..127
  const int shalf = tid & 1;     // staging k-half (16 elements)

  f32x4 acc[4][4];
#pragma unroll
  for (int a = 0; a < 4; ++a)
#pragma unroll
    for (int b = 0; b < 4; ++b) acc[a][b] = (f32x4){0.f, 0.f, 0.f, 0.f};

  const int gr = min(m0 + srow, N_NODES - 1);  // clamp tail-block loads

  for (int k0 = 0; k0 < IN_F; k0 += 32) {
    // global loads for this tile
    const float4* hp =
        reinterpret_cast<const float4*>(&h[gr * IN_F + k0 + shalf * 16]);
    const float4 h0 = hp[0], h1 = hp[1], h2 = hp[2], h3 = hp[3];
    const uint4* wp = reinterpret_cast<const uint4*>(
        &Wt16[srow * IN_F + k0 + shalf * 16]);
    const uint4 wv0 = wp[0], wv1 = wp[1];

    __syncthreads();  // previous tile's LDS reads complete
    {
      uint4 p0, p1;
      p0.x = cvt2(h0.x, h0.y); p0.y = cvt2(h0.z, h0.w);
      p0.z = cvt2(h1.x, h1.y); p0.w = cvt2(h1.z, h1.w);
      p1.x = cvt2(h2.x, h2.y); p1.y = cvt2(h2.z, h2.w);
      p1.z = cvt2(h3.x, h3.y); p1.w = cvt2(h3.z, h3.w);
      uint4* as = reinterpret_cast<uint4*>(&As[srow * AS_STRIDE + shalf * 16]);
      as[0] = p0; as[1] = p1;
      uint4* bs = reinterpret_cast<uint4*>(&Bs[srow * AS_STRIDE + shalf * 16]);
      bs[0] = wv0; bs[1] = wv1;
    }
    __syncthreads();

    bf16x8 af[4], bf[4];
#pragma unroll
    for (int t = 0; t < 4; ++t) {
      af[t] = *reinterpret_cast<const bf16x8*>(
          &As[(wr * 64 + t * 16 + lm) * AS_STRIDE + quad * 8]);
      bf[t] = *reinterpret_cast<const bf16x8*>(
          &Bs[(wc * 64 + t * 16 + lm) * AS_STRIDE + quad * 8]);
    }
#pragma unroll
    for (int tr = 0; tr < 4; ++tr)
#pragma unroll
      for (int tc = 0; tc < 4; ++tc)
        acc[tr][tc] = __builtin_amdgcn_mfma_f32_16x16x32_bf16(
            af[tr], bf[tc], acc[tr][tc], 0, 0, 0);
  }

  // ---- epilogue 1: fused f1/f2 (lane holds rows quad*4+reg per tile)
  float asv[4], adv[4];
#pragma unroll
  for (int tc = 0; tc < 4; ++tc) {
    asv[tc] = a_src[wc * 64 + tc * 16 + lm];
    adv[tc] = a_dst[wc * 64 + tc * 16 + lm];
  }
#pragma unroll
  for (int tr = 0; tr < 4; ++tr) {
#pragma unroll
    for (int reg = 0; reg < 4; ++reg) {
      float p1 = 0.f, p2 = 0.f;
#pragma unroll
      for (int tc = 0; tc < 4; ++tc) {
        p1 = fmaf(acc[tr][tc][reg], asv[tc], p1);
        p2 = fmaf(acc[tr][tc][reg], adv[tc], p2);
      }
#pragma unroll
      for (int o = 1; o < 16; o <<= 1) {  // reduce the 16 lm lanes
        p1 += __shfl_xor(p1, o);
        p2 += __shfl_xor(p2, o);
      }
      const int grow = m0 + wr * 64 + tr * 16 + quad * 4 + reg;
      if (lm == 0 && grow < N_NODES) {
        atomicAdd(&f1[grow], p1);
        atomicAdd(&f2[grow], p2);
      }
    }
  }

  // ---- epilogue 2: stage C tile to LDS (bf16), then coalesced global copy
  __syncthreads();  // done with As/Bs
#pragma unroll
  for (int tr = 0; tr < 4; ++tr)
#pragma unroll
    for (int tc = 0; tc < 4; ++tc)
#pragma unroll
      for (int reg = 0; reg < 4; ++reg)
        lds[(wr * 64 + tr * 16 + quad * 4 + reg) * OS_STRIDE + wc * 64 +
            tc * 16 + lm] = f32_to_bf16(acc[tr][tc][reg]);
  __syncthreads();
  // each (srow, shalf) thread copies 64 contiguous ushorts = 8 uint4
  if (m0 + srow < N_NODES) {
    uint4* dst =
        reinterpret_cast<uint4*>(&Wh16[(m0 + srow) * OUT_F + shalf * 64]);
    const uint4* src =
        reinterpret_cast<const uint4*>(&lds[srow * OS_STRIDE + shalf * 64]);
#pragma unroll
    for (int i = 0; i < 8; ++i) dst[i] = src[i];
  }
}

// ---------------------------------------------------------------------------
// Kernel 2: segment softmax + SpMM + ELU. One wave per node, 4 nodes/block.
// v4: v2's lane-owns-2-features layout, but pass C is unrolled x8 with the
// edge cache PADDED to a multiple of 8 ({att=0,col=0} entries) so every
// iteration is guard-free: 8 independent ds_read_b64 + 8 independent
// global_load_dword in flight per wave (latency-bound fix; R5 post-mortem).
// ---------------------------------------------------------------------------
__global__ __launch_bounds__(256) void gat_v4(
    const unsigned int* __restrict__ Whu,  // Wh16 viewed as dwords [N][64]
    const float* __restrict__ f1, const float* __restrict__ f2,
    const int* __restrict__ row_ptr, const int* __restrict__ col,
    float* __restrict__ out) {
  __shared__ int2 edge_s[4][128];

  const int w = threadIdx.x >> 6;
  const int lane = threadIdx.x & 63;
  const int node = blockIdx.x * 4 + w;

  const int start = row_ptr[node];
  const int deg = row_ptr[node + 1] - start;
  float2* outp = reinterpret_cast<float2*>(&out[node * OUT_F + lane * 2]);

  if (deg == 0) {
    *outp = make_float2(0.f, 0.f);
    return;
  }
  const float f1i = f1[node];
  float acc0 = 0.f, acc1 = 0.f;
  float m = -INFINITY, s = 0.f, inv;

  if (deg <= 128) {
    // pass A: logits -> LDS, running max
    for (int idx = lane; idx < deg; idx += 64) {
      const int c = col[start + idx];
      float v = f1i + f2[c];
      v = v > 0.f ? v : LRELU_ALPHA * v;
      edge_s[w][idx] = make_int2(__float_as_int(v), c);
      m = fmaxf(m, v);
    }
#pragma unroll
    for (int o = 32; o > 0; o >>= 1) m = fmaxf(m, __shfl_xor(m, o));
    __builtin_amdgcn_wave_barrier();
    // pass B: exp + sum (store numerator back)
    for (int idx = lane; idx < deg; idx += 64) {
      const float x = __expf(__int_as_float(edge_s[w][idx].x) - m);
      edge_s[w][idx].x = __float_as_int(x);
      s += x;
    }
#pragma unroll
    for (int o = 32; o > 0; o >>= 1) s += __shfl_xor(s, o);
    inv = 1.f / s;
    __builtin_amdgcn_wave_barrier();
    // pad to multiple of 8 with zero-contribution entries (att=0, col=0)
    const int padded = (deg + 7) & ~7;
    if (lane < padded - deg)
      edge_s[w][deg + lane] = make_int2(0, 0);  // 0.0f bits, row 0 (L2-hot)
    __builtin_amdgcn_wave_barrier();
    // pass C: guard-free, 8 edges per iteration, 8 gathers in flight
    for (int j = 0; j < padded; j += 8) {
      int2 e[8];
#pragma unroll
      for (int u = 0; u < 8; ++u) e[u] = edge_s[w][j + u];
      unsigned g[8];
#pragma unroll
      for (int u = 0; u < 8; ++u) g[u] = Whu[e[u].y * 64 + lane];
#pragma unroll
      for (int u = 0; u < 8; ++u) {
        const float a = __int_as_float(e[u].x);
        acc0 = fmaf(a, __uint_as_float(g[u] << 16), acc0);
        acc1 = fmaf(a, __uint_as_float(g[u] & 0xffff0000u), acc1);
      }
    }
  } else {
    // slow path (deg > 128, ~never at mean degree 16): 3-pass recompute
    for (int idx = lane; idx < deg; idx += 64) {
      float v = f1i + f2[col[start + idx]];
      v = v > 0.f ? v : LRELU_ALPHA * v;
      m = fmaxf(m, v);
    }
#pragma unroll
    for (int o = 32; o > 0; o >>= 1) m = fmaxf(m, __shfl_xor(m, o));
    for (int idx = lane; idx < deg; idx += 64) {
      float v = f1i + f2[col[start + idx]];
      v = v > 0.f ? v : LRELU_ALPHA * v;
      s += __expf(v - m);
    }
#pragma unroll
    for (int o = 32; o > 0; o >>= 1) s += __shfl_xor(s, o);
    inv = 1.f / s;
    for (int j = 0; j < deg; ++j) {
      const int c = col[start + j];
      float v = f1i + f2[c];
      v = v > 0.f ? v : LRELU_ALPHA * v;
      const float a = __expf(v - m);
      const unsigned g = Whu[c * 64 + lane];
      acc0 = fmaf(a, __uint_as_float(g << 16), acc0);
      acc1 = fmaf(a, __uint_as_float(g & 0xffff0000u), acc1);
    }
  }
  acc0 *= inv;
  acc1 *= inv;
  const float o0 = acc0 > 0.f ? acc0 : expm1f(acc0);
  const float o1 = acc1 > 0.f ? acc1 : expm1f(acc1);
  *outp = make_float2(o0, o1);
}

// ---------------------------------------------------------------------------
extern "C" void kernel_launch(void* const* d_in, const int* in_sizes, int n_in,
                              void* d_out, int out_size, void* d_ws,
                              size_t ws_size, hipStream_t stream) {
  const float* h     = (const float*)d_in[0];
  const float* W     = (const float*)d_in[1];
  const float* a_src = (const float*)d_in[2];
  const float* a_dst = (const float*)d_in[3];
  const int*   row   = (const int*)d_in[4];
  const int*   col   = (const int*)d_in[5];
  float* out = (float*)d_out;

  char* ws = (char*)d_ws;
  unsigned short* Wh16 = (unsigned short*)(ws);        // N*128*2 = 25,600,000 B
  float* f1      = (float*)(ws + 25600000);            //    400,000 B
  float* f2      = (float*)(ws + 26000000);            //    400,000 B
  int*   row_ptr = (int*)  (ws + 26400000);            //    400,004 B
  unsigned short* Wt16 = (unsigned short*)(ws + 26800016);  // 64 KB, align16

  hipLaunchKernelGGL(prep_kernel, dim3(ROWPTR_BLOCKS + 128), dim3(256), 0,
                     stream, row, row_ptr, f1, f2, W, Wt16);
  hipLaunchKernelGGL(gemm_mfma, dim3((N_NODES + 127) / 128), dim3(256), 0,
                     stream, h, Wt16, a_src, a_dst, Wh16, f1, f2);
  hipLaunchKernelGGL(gat_v4, dim3(N_NODES / 4), dim3(256), 0, stream,
                     (const unsigned int*)Wh16, f1, f2, row_ptr, col, out);
}